// Round 3
// baseline (175.173 us; speedup 1.0000x reference)
//
#include <hip/hip_runtime.h>

// NeurTWs R13: target = 4 blocks/CU WITHOUT spill. Model from R10/R11/R12:
// waves/SIMD = floor(512 / (archVGPR + AGPR)). R10: 84+64=148 -> 3 waves
// (61us, grid-768 tail). R11: launch_bounds(256,4) forced arch 64 -> 4
// waves resident (occ 40%, 3.5 TB/s sustained!) but ~20 regs SPILLED
// (WRITE 11->81MB) -> 90us. R12: 84+64 @ grid 1024 -> 3 resident + 256-
// block tail at 1/CU -> 77us. Conclusion: the machine is latency-bound and
// converts waves to BW (2.4->3.5 TB/s proven); the only blocker is ~20
// arch VGPRs. R13 removes them structurally so (256,4) compiles clean:
//  - persistent weight frags (b_w2/b2/bm1/wm2, 18 regs) -> LDS (cw2/cb2/
//    cbm1/cwm2, +2.7KB -> 36.5KB/block, 4x fits 160KB), re-read per iter;
//    opaque oz (asm "+v") in indices defeats LICM re-hoisting.
//  - fA prefetch halved 32->16 regs: rt01 loaded at iter top; rt23 issued
//    mid-GEMM3 after rt01 consumed, covered by pe-ktile MFMAs + 4-wave TLP.
//  - GEMM2 streamed per-ct (no pc[4][2] array; AGPR peak = acc 64 only);
//    pe-ktile reads a_pe per-rt (4 regs not 16).
// Expected: arch ~60, total 124 -> 4 waves/SIMD, grid 1024 zero-tail,
// ~42-50us. If WRITE_SIZE >> 13MB the spill persists and this is reverted.
// Fragment layouts (gfx950, verified): A/B: idx=lane&15, k=(lane>>4)*8+j;
// C/D: col=lane&15, row=(lane>>4)*4+reg.

typedef _Float16 half8 __attribute__((ext_vector_type(8)));
typedef float floatx4 __attribute__((ext_vector_type(4)));

#define HSTR 40    // h/pe row stride (f16): 80 B
#define WSTR 104   // wm1t row stride (f16): 208 B
#define GRID_MAIN 1024

__global__ void feat_to_f16(const float* __restrict__ nf,
                            _Float16* __restrict__ o, int n8) {
    int t = blockIdx.x * 256 + threadIdx.x;
    if (t >= n8) return;
    const float4* p = (const float4*)nf + (size_t)t * 2;
    const float4 a = p[0], b = p[1];
    half8 h;
    h[0] = (_Float16)a.x; h[1] = (_Float16)a.y;
    h[2] = (_Float16)a.z; h[3] = (_Float16)a.w;
    h[4] = (_Float16)b.x; h[5] = (_Float16)b.y;
    h[6] = (_Float16)b.z; h[7] = (_Float16)b.w;
    *((half8*)o + t) = h;
}

__global__ __launch_bounds__(256, 4) void neurtw_r13(
    const float* __restrict__ pos_table,   // [NUM_KEYS, 4]
    const float* __restrict__ node_feat,   // [NUM_NODES, 64] fp32 (fallback)
    const float* __restrict__ W1,          // [4, 32]
    const float* __restrict__ b1,          // [32]
    const float* __restrict__ W2,          // [32, 32]
    const float* __restrict__ b2,          // [32]
    const float* __restrict__ Wm1,         // [96, 64]
    const float* __restrict__ bm1,         // [64]
    const float* __restrict__ Wm2,         // [64, 1]
    const float* __restrict__ bm2,         // [1]
    const int*   __restrict__ key_idx,     // [rows]
    const int*   __restrict__ node_idx,    // [rows]
    const _Float16* __restrict__ feat16,   // [NUM_NODES, 64] f16 (ws)
    int use_f16,
    float*       __restrict__ out,         // [rows]
    int rows)
{
    __shared__ _Float16 hpe[256 * HSTR];   // 20480 B (h then pe; wave-private)
    __shared__ _Float16 wm1t[64 * WSTR];   // 13312 B  wm1t[n][k] = Wm1[k][n]
    __shared__ _Float16 cw2[2 * 64 * 8];   //  2048 B  per-lane W2 B-fragments
    __shared__ float    cb2[32];           //   128 B
    __shared__ float    cbm1[64];          //   256 B
    __shared__ float    cwm2[64];          //   256 B

    const int tid  = threadIdx.x;
    const int lane = tid & 63;
    const int r0   = (tid >> 6) * 64;
    const int ln   = lane & 15;
    const int q    = lane >> 4;

    // ---------- once per block: stage Wm1^T into LDS ----------
    #pragma unroll
    for (int i = 0; i < 3; ++i) {
        const int task = i * 256 + tid;
        const int n = task & 63, k8 = task >> 6;
        half8 w;
        #pragma unroll
        for (int kk = 0; kk < 8; ++kk)
            w[kk] = (_Float16)Wm1[(k8 * 8 + kk) * 64 + n];
        *(half8*)(&wm1t[n * WSTR + k8 * 8]) = w;
    }

    // ---------- once per block: small weight/bias tables -> LDS ----------
    if (tid < 128) {                       // cw2[ct][lane][8]
        const int ct = tid >> 6, l = tid & 63;
        const int lq = l >> 4, lln = l & 15;
        half8 w;
        #pragma unroll
        for (int j = 0; j < 8; ++j)
            w[j] = (_Float16)W2[(lq * 8 + j) * 32 + ct * 16 + lln];
        *(half8*)(&cw2[ct * 512 + l * 8]) = w;
    }
    if (tid < 32) cb2[tid] = b2[tid];
    if (tid >= 128 && tid < 192) {
        const int t = tid - 128;
        cbm1[t] = bm1[t];
        cwm2[t] = Wm2[t];
    }
    const float bm2s = bm2[0];

    __syncthreads();   // LDS tables staged (the ONLY barrier in the kernel)

    for (int base = blockIdx.x * 256; base < rows; base += GRID_MAIN * 256) {
        const int row = base + tid;

        // opaque zero: defeats LICM on the LDS const-table reads so they
        // stay in-loop (compiler would otherwise hoist them back to regs)
        int oz = 0;
        asm volatile("" : "+v"(oz));

        // ---- node indices + first-half feat prefetch (rt 0,1) ----
        int ndr[4];
        #pragma unroll
        for (int rt = 0; rt < 4; ++rt)
            ndr[rt] = node_idx[base + r0 + rt * 16 + ln];

        half8 fA01[2][2];
        if (use_f16) {
            #pragma unroll
            for (int rt = 0; rt < 2; ++rt) {
                const _Float16* fb = feat16 + (size_t)ndr[rt] * 64 + q * 8;
                fA01[rt][0] = *(const half8*)(fb);
                fA01[rt][1] = *(const half8*)(fb + 32);
            }
        } else {
            #pragma unroll
            for (int rt = 0; rt < 2; ++rt) {
                const float* fb = node_feat + (size_t)ndr[rt] * 64 + q * 8;
                #pragma unroll
                for (int kt = 0; kt < 2; ++kt) {
                    const float4 lo = *(const float4*)(fb + kt * 32);
                    const float4 hi = *(const float4*)(fb + kt * 32 + 4);
                    half8 h;
                    h[0] = (_Float16)lo.x; h[1] = (_Float16)lo.y;
                    h[2] = (_Float16)lo.z; h[3] = (_Float16)lo.w;
                    h[4] = (_Float16)hi.x; h[5] = (_Float16)hi.y;
                    h[6] = (_Float16)hi.z; h[7] = (_Float16)hi.w;
                    fA01[rt][kt] = h;
                }
            }
        }

        const int kk = key_idx[row];
        const float4 enc = *(const float4*)(pos_table + (size_t)kk * 4);

        // ---- GEMM1 (VALU fp32, uniform weights via s_load) -> h ----
        #pragma unroll
        for (int g = 0; g < 4; ++g) {
            half8 hv;
            #pragma unroll
            for (int j8 = 0; j8 < 8; ++j8) {
                const int j = g * 8 + j8;
                float a = fmaf(enc.w, W1[96 + j],
                          fmaf(enc.z, W1[64 + j],
                          fmaf(enc.y, W1[32 + j],
                          fmaf(enc.x, W1[j], b1[j]))));
                hv[j8] = (_Float16)fmaxf(a, 0.0f);
            }
            *(half8*)(&hpe[tid * HSTR + g * 8]) = hv;
        }
        // wave-private transpose read — no barrier (same wave wrote it)
        half8 a_h[4];
        #pragma unroll
        for (int rt = 0; rt < 4; ++rt)
            a_h[rt] = *(const half8*)(&hpe[(r0 + rt * 16 + ln) * HSTR + q * 8]);

        // ---- GEMM2 streamed per-ct: 8 MFMA -> pe written immediately ----
        #pragma unroll
        for (int ct = 0; ct < 2; ++ct) {
            const half8 bw2 = *(const half8*)(&cw2[ct * 512 + lane * 8 + oz]);
            const float vb2 = cb2[ct * 16 + ln + oz];
            #pragma unroll
            for (int rt = 0; rt < 4; ++rt) {
                floatx4 c = {0.f, 0.f, 0.f, 0.f};
                floatx4 pcv = __builtin_amdgcn_mfma_f32_16x16x32_f16(
                    a_h[rt], bw2, c, 0, 0, 0);
                #pragma unroll
                for (int r = 0; r < 4; ++r)
                    hpe[(r0 + rt * 16 + q * 4 + r) * HSTR + ct * 16 + ln] =
                        (_Float16)(pcv[r] + vb2);
            }
        }
        // no barrier: reader below is the same wave

        // ---- GEMM3: 48 MFMA, split so only half the fA regs are live ----
        floatx4 acc[4][4];
        #pragma unroll
        for (int ct = 0; ct < 4; ++ct) {
            const float bb = cbm1[ct * 16 + ln + oz];
            #pragma unroll
            for (int rt = 0; rt < 4; ++rt)
                acc[rt][ct] = (floatx4){bb, bb, bb, bb};
        }

        // feat ktiles for rt 0,1 (consume fA01)
        #pragma unroll
        for (int kt = 0; kt < 2; ++kt) {
            half8 bk[4];
            #pragma unroll
            for (int ct = 0; ct < 4; ++ct)
                bk[ct] = *(const half8*)(&wm1t[(ct * 16 + ln) * WSTR + 32 + kt * 32 + q * 8]);
            #pragma unroll
            for (int rt = 0; rt < 2; ++rt)
                #pragma unroll
                for (int ct = 0; ct < 4; ++ct)
                    acc[rt][ct] = __builtin_amdgcn_mfma_f32_16x16x32_f16(
                        fA01[rt][kt], bk[ct], acc[rt][ct], 0, 0, 0);
        }

        // issue second-half feat loads (rt 2,3); latency covered by the
        // pe-ktile below + 4-waves/SIMD interleave
        half8 fA23[2][2];
        if (use_f16) {
            #pragma unroll
            for (int rr = 0; rr < 2; ++rr) {
                const _Float16* fb = feat16 + (size_t)ndr[2 + rr] * 64 + q * 8;
                fA23[rr][0] = *(const half8*)(fb);
                fA23[rr][1] = *(const half8*)(fb + 32);
            }
        } else {
            #pragma unroll
            for (int rr = 0; rr < 2; ++rr) {
                const float* fb = node_feat + (size_t)ndr[2 + rr] * 64 + q * 8;
                #pragma unroll
                for (int kt = 0; kt < 2; ++kt) {
                    const float4 lo = *(const float4*)(fb + kt * 32);
                    const float4 hi = *(const float4*)(fb + kt * 32 + 4);
                    half8 h;
                    h[0] = (_Float16)lo.x; h[1] = (_Float16)lo.y;
                    h[2] = (_Float16)lo.z; h[3] = (_Float16)lo.w;
                    h[4] = (_Float16)hi.x; h[5] = (_Float16)hi.y;
                    h[6] = (_Float16)hi.z; h[7] = (_Float16)hi.w;
                    fA23[rr][kt] = h;
                }
            }
        }

        // pe ktile (A = pe from LDS, per-rt a_pe to keep regs low)
        {
            half8 b0[4];
            #pragma unroll
            for (int ct = 0; ct < 4; ++ct)
                b0[ct] = *(const half8*)(&wm1t[(ct * 16 + ln) * WSTR + q * 8]);
            #pragma unroll
            for (int rt = 0; rt < 4; ++rt) {
                const half8 ap = *(const half8*)(&hpe[(r0 + rt * 16 + ln) * HSTR + q * 8]);
                #pragma unroll
                for (int ct = 0; ct < 4; ++ct)
                    acc[rt][ct] = __builtin_amdgcn_mfma_f32_16x16x32_f16(
                        ap, b0[ct], acc[rt][ct], 0, 0, 0);
            }
        }

        // feat ktiles for rt 2,3 (consume fA23; bk re-read from LDS)
        #pragma unroll
        for (int kt = 0; kt < 2; ++kt) {
            half8 bk[4];
            #pragma unroll
            for (int ct = 0; ct < 4; ++ct)
                bk[ct] = *(const half8*)(&wm1t[(ct * 16 + ln) * WSTR + 32 + kt * 32 + q * 8]);
            #pragma unroll
            for (int rr = 0; rr < 2; ++rr)
                #pragma unroll
                for (int ct = 0; ct < 4; ++ct)
                    acc[2 + rr][ct] = __builtin_amdgcn_mfma_f32_16x16x32_f16(
                        fA23[rr][kt], bk[ct], acc[2 + rr][ct], 0, 0, 0);
        }

        // ---- GEMM4: relu + Wm2 dot + 4-step butterfly + store ----
        float wv[4];
        #pragma unroll
        for (int ct = 0; ct < 4; ++ct)
            wv[ct] = cwm2[ct * 16 + ln + oz];

        #pragma unroll
        for (int rt = 0; rt < 4; ++rt) {
            #pragma unroll
            for (int r = 0; r < 4; ++r) {
                float p = 0.0f;
                #pragma unroll
                for (int ct = 0; ct < 4; ++ct)
                    p = fmaf(fmaxf(acc[rt][ct][r], 0.0f), wv[ct], p);
                p += __shfl_xor(p, 1);
                p += __shfl_xor(p, 2);
                p += __shfl_xor(p, 4);
                p += __shfl_xor(p, 8);
                if (ln == 0)
                    out[base + r0 + rt * 16 + q * 4 + r] = p + bm2s;
            }
        }
    }
}

extern "C" void kernel_launch(void* const* d_in, const int* in_sizes, int n_in,
                              void* d_out, int out_size, void* d_ws, size_t ws_size,
                              hipStream_t stream) {
    const float* pos_table = (const float*)d_in[0];
    const float* node_feat = (const float*)d_in[1];
    const float* W1        = (const float*)d_in[2];
    const float* b1        = (const float*)d_in[3];
    const float* W2        = (const float*)d_in[4];
    const float* b2        = (const float*)d_in[5];
    const float* Wm1       = (const float*)d_in[6];
    const float* bm1       = (const float*)d_in[7];
    const float* Wm2       = (const float*)d_in[8];
    const float* bm2       = (const float*)d_in[9];
    const int*   key_idx   = (const int*)d_in[10];
    const int*   node_idx  = (const int*)d_in[11];
    float* out = (float*)d_out;

    const int rows  = in_sizes[10];                // 1,048,576
    const int nfeat = in_sizes[1];                 // NUM_NODES*64

    _Float16* feat16 = (_Float16*)d_ws;
    const size_t need = (size_t)nfeat * sizeof(_Float16);
    const int use_f16 = (ws_size >= need) ? 1 : 0;

    if (use_f16) {
        const int n8 = nfeat / 8;
        feat_to_f16<<<(n8 + 255) / 256, 256, 0, stream>>>(node_feat, feat16, n8);
    }

    neurtw_r13<<<GRID_MAIN, 256, 0, stream>>>(
        pos_table, node_feat, W1, b1, W2, b2, Wm1, bm1, Wm2, bm2,
        key_idx, node_idx, feat16, use_f16, out, rows);
}

// Round 4
// 156.770 us; speedup vs baseline: 1.1174x; 1.1174x over previous
//
#include <hip/hip_runtime.h>

// NeurTWs R14 = R10 body (proven 61us, 148 regs, no spill, 3 blocks/CU)
// + cross-iteration index/enc prefetch. R11/R13 post-mortems: forcing 4
// waves/SIMD via launch_bounds(256,4) ALWAYS spills (~16-20 regs: fA is 32
// VGPRs, a_h 16, acc 64 AGPR -- body genuinely needs ~148) and spill
// traffic (WRITE 11->69..81MB) negates the occupancy gain. But R11/R13
// proved waves->BW conversion works (2.4 -> 3.3-3.5 TB/s sustained), i.e.
// we are latency/MLP-bound, ~43us floor at 147MB / 3.4TB/s.
// R14 buys outstanding-load parallelism WITHIN the 3-wave budget instead:
// (256,3) allows 170 regs/wave, R10 used 148 -> 22 free. Spend 9 on
// prefetching next-iter ndr[4]/kk/enc. Effect per iteration:
//  - feat gathers issue at cycle 0 (ndr already resident; R10 stalled
//    ~500cy on node_idx before they could issue),
//  - GEMM1 starts immediately (enc resident; R10 stalled ~800cy on the
//    key_idx->pos_table chain),
//  - enc_next issues mid-iter after kk_next had GEMM1+GEMM2 to arrive.
// Grid stays 768 (R12: grid 1024 @ 3-resident = tail regression).
// Everything else byte-for-byte R10. Fragment layouts (gfx950, verified):
// A/B: idx=lane&15, k=(lane>>4)*8+j; C/D: col=lane&15, row=(lane>>4)*4+reg.

typedef _Float16 half8 __attribute__((ext_vector_type(8)));
typedef float floatx4 __attribute__((ext_vector_type(4)));

#define HSTR 40    // h/pe row stride (f16): 80 B
#define WSTR 104   // wm1t row stride (f16): 208 B
#define GRID_MAIN 768

__global__ void feat_to_f16(const float* __restrict__ nf,
                            _Float16* __restrict__ o, int n8) {
    int t = blockIdx.x * 256 + threadIdx.x;
    if (t >= n8) return;
    const float4* p = (const float4*)nf + (size_t)t * 2;
    const float4 a = p[0], b = p[1];
    half8 h;
    h[0] = (_Float16)a.x; h[1] = (_Float16)a.y;
    h[2] = (_Float16)a.z; h[3] = (_Float16)a.w;
    h[4] = (_Float16)b.x; h[5] = (_Float16)b.y;
    h[6] = (_Float16)b.z; h[7] = (_Float16)b.w;
    *((half8*)o + t) = h;
}

__device__ __forceinline__ void load_feat(const _Float16* __restrict__ feat16,
                                          const float* __restrict__ node_feat,
                                          int use_f16, const int* ndr, int q,
                                          half8 fA[4][2]) {
    if (use_f16) {
        #pragma unroll
        for (int rt = 0; rt < 4; ++rt) {
            const _Float16* fb = feat16 + (size_t)ndr[rt] * 64 + q * 8;
            fA[rt][0] = *(const half8*)(fb);
            fA[rt][1] = *(const half8*)(fb + 32);
        }
    } else {
        #pragma unroll
        for (int rt = 0; rt < 4; ++rt) {
            const float* fb = node_feat + (size_t)ndr[rt] * 64 + q * 8;
            #pragma unroll
            for (int kt = 0; kt < 2; ++kt) {
                const float4 lo = *(const float4*)(fb + kt * 32);
                const float4 hi = *(const float4*)(fb + kt * 32 + 4);
                half8 h;
                h[0] = (_Float16)lo.x; h[1] = (_Float16)lo.y;
                h[2] = (_Float16)lo.z; h[3] = (_Float16)lo.w;
                h[4] = (_Float16)hi.x; h[5] = (_Float16)hi.y;
                h[6] = (_Float16)hi.z; h[7] = (_Float16)hi.w;
                fA[rt][kt] = h;
            }
        }
    }
}

__global__ __launch_bounds__(256, 3) void neurtw_r14(
    const float* __restrict__ pos_table,   // [NUM_KEYS, 4]
    const float* __restrict__ node_feat,   // [NUM_NODES, 64] fp32 (fallback)
    const float* __restrict__ W1,          // [4, 32]
    const float* __restrict__ b1,          // [32]
    const float* __restrict__ W2,          // [32, 32]
    const float* __restrict__ b2,          // [32]
    const float* __restrict__ Wm1,         // [96, 64]
    const float* __restrict__ bm1,         // [64]
    const float* __restrict__ Wm2,         // [64, 1]
    const float* __restrict__ bm2,         // [1]
    const int*   __restrict__ key_idx,     // [rows]
    const int*   __restrict__ node_idx,    // [rows]
    const _Float16* __restrict__ feat16,   // [NUM_NODES, 64] f16 (ws)
    int use_f16,
    float*       __restrict__ out,         // [rows]
    int rows)
{
    __shared__ _Float16 hpe[256 * HSTR];   // 20 KB (h then pe; wave-private)
    __shared__ _Float16 wm1t[64 * WSTR];   // 13 KB  wm1t[n][k] = Wm1[k][n]

    const int tid  = threadIdx.x;
    const int lane = tid & 63;
    const int r0   = (tid >> 6) * 64;
    const int ln   = lane & 15;
    const int q    = lane >> 4;

    // ---------- once per block: stage Wm1^T into LDS ----------
    #pragma unroll
    for (int i = 0; i < 3; ++i) {
        const int task = i * 256 + tid;
        const int n = task & 63, k8 = task >> 6;
        half8 w;
        #pragma unroll
        for (int kk = 0; kk < 8; ++kk)
            w[kk] = (_Float16)Wm1[(k8 * 8 + kk) * 64 + n];
        *(half8*)(&wm1t[n * WSTR + k8 * 8]) = w;
    }

    // ---------- once per block: per-lane weight/bias fragments ----------
    half8 b_w2[2];
    #pragma unroll
    for (int ct = 0; ct < 2; ++ct)
        #pragma unroll
        for (int j = 0; j < 8; ++j)
            b_w2[ct][j] = (_Float16)W2[(q * 8 + j) * 32 + ct * 16 + ln];
    float b2v[2];
    b2v[0] = b2[ln]; b2v[1] = b2[16 + ln];
    float bm1v[4], wm2v[4];
    #pragma unroll
    for (int ct = 0; ct < 4; ++ct) {
        bm1v[ct] = bm1[ct * 16 + ln];
        wm2v[ct] = Wm2[ct * 16 + ln];
    }
    const float bm2s = bm2[0];

    __syncthreads();   // wm1t staged (the ONLY barrier in the kernel)

    // ---------- pipeline prologue: iter-0 indices + enc ----------
    int base = blockIdx.x * 256;
    int ndr[4];
    #pragma unroll
    for (int rt = 0; rt < 4; ++rt)
        ndr[rt] = node_idx[base + r0 + rt * 16 + ln];
    int kkc = key_idx[base + tid];
    float4 enc = *(const float4*)(pos_table + (size_t)kkc * 4);

    while (base < rows) {
        const int nbase = base + GRID_MAIN * 256;
        const bool more = nbase < rows;

        // ---- 1) current feat gathers: issue at cycle 0 (ndr resident) ----
        half8 fA[4][2];
        load_feat(feat16, node_feat, use_f16, ndr, q, fA);

        // ---- 2) next-iter independent index loads ----
        int ndr_n[4];
        int kk_n;
        if (more) {
            #pragma unroll
            for (int rt = 0; rt < 4; ++rt)
                ndr_n[rt] = node_idx[nbase + r0 + rt * 16 + ln];
            kk_n = key_idx[nbase + tid];
        } else {
            #pragma unroll
            for (int rt = 0; rt < 4; ++rt)
                ndr_n[rt] = 0;
            kk_n = 0;
        }

        // ---- GEMM1 (VALU fp32, enc already resident) -> h ----
        #pragma unroll
        for (int g = 0; g < 4; ++g) {
            half8 hv;
            #pragma unroll
            for (int j8 = 0; j8 < 8; ++j8) {
                const int j = g * 8 + j8;
                float a = fmaf(enc.w, W1[96 + j],
                          fmaf(enc.z, W1[64 + j],
                          fmaf(enc.y, W1[32 + j],
                          fmaf(enc.x, W1[j], b1[j]))));
                hv[j8] = (_Float16)fmaxf(a, 0.0f);
            }
            *(half8*)(&hpe[tid * HSTR + g * 8]) = hv;
        }
        // wave-private transpose read — no barrier (same wave wrote it)
        half8 a_h[4];
        #pragma unroll
        for (int rt = 0; rt < 4; ++rt)
            a_h[rt] = *(const half8*)(&hpe[(r0 + rt * 16 + ln) * HSTR + q * 8]);

        // ---- GEMM2: 8 MFMA -> pe (C-layout regs) ----
        floatx4 pc[4][2];
        #pragma unroll
        for (int rt = 0; rt < 4; ++rt)
            #pragma unroll
            for (int ct = 0; ct < 2; ++ct) {
                floatx4 c = {0.f, 0.f, 0.f, 0.f};
                pc[rt][ct] = __builtin_amdgcn_mfma_f32_16x16x32_f16(
                    a_h[rt], b_w2[ct], c, 0, 0, 0);
            }

        // write pe into the SAME buffer (h consumed; own wave's slice only)
        #pragma unroll
        for (int rt = 0; rt < 4; ++rt)
            #pragma unroll
            for (int ct = 0; ct < 2; ++ct)
                #pragma unroll
                for (int r = 0; r < 4; ++r)
                    hpe[(r0 + rt * 16 + q * 4 + r) * HSTR + ct * 16 + ln] =
                        (_Float16)(pc[rt][ct][r] + b2v[ct]);
        // no barrier: reader below is the same wave

        // ---- 5) next-iter enc gather (kk_n has had GEMM1+GEMM2 to land) ----
        float4 enc_n = enc;
        if (more)
            enc_n = *(const float4*)(pos_table + (size_t)kk_n * 4);

        // ---- GEMM3: 48 MFMA ----
        floatx4 acc[4][4];
        #pragma unroll
        for (int ct = 0; ct < 4; ++ct) {
            const float bb = bm1v[ct];
            #pragma unroll
            for (int rt = 0; rt < 4; ++rt)
                acc[rt][ct] = (floatx4){bb, bb, bb, bb};
        }

        {   // ktile 0: A = pe from LDS
            half8 a_pe[4];
            #pragma unroll
            for (int rt = 0; rt < 4; ++rt)
                a_pe[rt] = *(const half8*)(&hpe[(r0 + rt * 16 + ln) * HSTR + q * 8]);
            half8 b0[4];
            #pragma unroll
            for (int ct = 0; ct < 4; ++ct)
                b0[ct] = *(const half8*)(&wm1t[(ct * 16 + ln) * WSTR + q * 8]);
            #pragma unroll
            for (int rt = 0; rt < 4; ++rt)
                #pragma unroll
                for (int ct = 0; ct < 4; ++ct)
                    acc[rt][ct] = __builtin_amdgcn_mfma_f32_16x16x32_f16(
                        a_pe[rt], b0[ct], acc[rt][ct], 0, 0, 0);
        }

        #pragma unroll
        for (int kt = 0; kt < 2; ++kt) {   // ktiles 1,2: A = feat (prefetched)
            half8 bk[4];
            #pragma unroll
            for (int ct = 0; ct < 4; ++ct)
                bk[ct] = *(const half8*)(&wm1t[(ct * 16 + ln) * WSTR + 32 + kt * 32 + q * 8]);
            #pragma unroll
            for (int rt = 0; rt < 4; ++rt)
                #pragma unroll
                for (int ct = 0; ct < 4; ++ct)
                    acc[rt][ct] = __builtin_amdgcn_mfma_f32_16x16x32_f16(
                        fA[rt][kt], bk[ct], acc[rt][ct], 0, 0, 0);
        }

        // ---- GEMM4: relu + Wm2 dot + 4-step butterfly + store ----
        #pragma unroll
        for (int rt = 0; rt < 4; ++rt) {
            #pragma unroll
            for (int r = 0; r < 4; ++r) {
                float p = 0.0f;
                #pragma unroll
                for (int ct = 0; ct < 4; ++ct)
                    p = fmaf(fmaxf(acc[rt][ct][r], 0.0f), wm2v[ct], p);
                p += __shfl_xor(p, 1);
                p += __shfl_xor(p, 2);
                p += __shfl_xor(p, 4);
                p += __shfl_xor(p, 8);
                if (ln == 0)
                    out[base + r0 + rt * 16 + q * 4 + r] = p + bm2s;
            }
        }

        // ---- rotate pipeline state ----
        base = nbase;
        #pragma unroll
        for (int rt = 0; rt < 4; ++rt)
            ndr[rt] = ndr_n[rt];
        kkc = kk_n;
        enc = enc_n;
    }
}

extern "C" void kernel_launch(void* const* d_in, const int* in_sizes, int n_in,
                              void* d_out, int out_size, void* d_ws, size_t ws_size,
                              hipStream_t stream) {
    const float* pos_table = (const float*)d_in[0];
    const float* node_feat = (const float*)d_in[1];
    const float* W1        = (const float*)d_in[2];
    const float* b1        = (const float*)d_in[3];
    const float* W2        = (const float*)d_in[4];
    const float* b2        = (const float*)d_in[5];
    const float* Wm1       = (const float*)d_in[6];
    const float* bm1       = (const float*)d_in[7];
    const float* Wm2       = (const float*)d_in[8];
    const float* bm2       = (const float*)d_in[9];
    const int*   key_idx   = (const int*)d_in[10];
    const int*   node_idx  = (const int*)d_in[11];
    float* out = (float*)d_out;

    const int rows  = in_sizes[10];                // 1,048,576
    const int nfeat = in_sizes[1];                 // NUM_NODES*64

    _Float16* feat16 = (_Float16*)d_ws;
    const size_t need = (size_t)nfeat * sizeof(_Float16);
    const int use_f16 = (ws_size >= need) ? 1 : 0;

    if (use_f16) {
        const int n8 = nfeat / 8;
        feat_to_f16<<<(n8 + 255) / 256, 256, 0, stream>>>(node_feat, feat16, n8);
    }

    neurtw_r14<<<GRID_MAIN, 256, 0, stream>>>(
        pos_table, node_feat, W1, b1, W2, b2, Wm1, bm1, Wm2, bm2,
        key_idx, node_idx, feat16, use_f16, out, rows);
}